// Round 12
// baseline (5546.331 us; speedup 1.0000x reference)
//
#include <hip/hip_runtime.h>
#include <hip/hip_bf16.h>
#include <hip/hip_cooperative_groups.h>

#define NV 128
#define NE 256
#define HD 1024
#define NB 32
#define NS 1024

typedef unsigned short u16;
typedef unsigned short ushort8 __attribute__((ext_vector_type(8)));
typedef unsigned short u16x4 __attribute__((ext_vector_type(4)));
typedef short bf16x8 __attribute__((ext_vector_type(8)));
typedef float f32x4 __attribute__((ext_vector_type(4)));

#define MFMA16(a, b, c) __builtin_amdgcn_mfma_f32_16x16x32_bf16(a, b, c, 0, 0, 0)

__device__ __forceinline__ float bf2f(u16 u){
  unsigned int x = ((unsigned int)u) << 16;
  return __builtin_bit_cast(float, x);
}
__device__ __forceinline__ u16 f2bf(float f){
  unsigned int u = __builtin_bit_cast(unsigned int, f);
  unsigned int r = u + 0x7fffu + ((u >> 16) & 1u);
  return (u16)(r >> 16);
}

// ---------------- K0: fp32 weights -> bf16 copies ----------------
__global__ __launch_bounds__(256) void k_cvt(const float* __restrict__ waw,
    const float* __restrict__ fcw, u16* __restrict__ wa_bf, u16* __restrict__ fc_bf)
{
  const int i = blockIdx.x * 256 + threadIdx.x;
  if (i < 1048576) wa_bf[i] = f2bf(waw[i]);
  const int j = i - 1048576;
  if (j >= 0 && j < 262144) fc_bf[j] = f2bf(fcw[j]);
}

// ---------------- K1: XW[v,h] = sum_e emb[v,e]*Wx[h,e] + Wx_b[h] ----------------
__global__ __launch_bounds__(256) void k_xw(const float* __restrict__ emb,
    const float* __restrict__ wxw, const float* __restrict__ wxb,
    float* __restrict__ XW)
{
  __shared__ float es[NE];
  const int v = blockIdx.x;
  for (int i = threadIdx.x; i < NE; i += 256) es[i] = emb[v*NE + i];
  __syncthreads();
  for (int h = threadIdx.x; h < HD; h += 256){
    const float* wr = wxw + (size_t)h * NE;
    float acc = 0.f;
#pragma unroll 4
    for (int e = 0; e < NE; e += 4){
      float4 w4 = *reinterpret_cast<const float4*>(wr + e);
      acc += w4.x*es[e] + w4.y*es[e+1] + w4.z*es[e+2] + w4.w*es[e+3];
    }
    XW[(size_t)v*HD + h] = acc + wxb[h];
  }
}

// ---------------- K2: RNN scan (R11 + hstate x2 replication + XW prefetch) ------
// 256 WGs x 256 thr, 8 groups of 32 WGs; group g = bid&7 owns batches 4g..4g+3.
// R=4 rows x K=32 tiling (kc = tid&31, rg = tid>>5).
// Exchange: fence-free (R11-proven). NEW: hstate replicated x2 — producers WT-store
// each h value to both replicas; consumer m reads replica m&1, halving the per-IC-line
// read fan-in (32 synchronized WGs re-reading the same 16KB was the suspected
// hot-spot). XW gather for step t+1 issued before the end-of-step barrier.
__global__ __launch_bounds__(256, 2) void k_scan2(const int* __restrict__ x,
    const float* __restrict__ whw, const float* __restrict__ whb,
    const float* __restrict__ XW, float* __restrict__ hstate,
    u16* __restrict__ Harc, unsigned int* __restrict__ cnt)
{
  __shared__ __align__(16) float hs[4096];   // 4 batches x 1024
  __shared__ int xs[4096];                   // 4 batches x 1024 token ids
  const int tid = threadIdx.x;
  const int g = blockIdx.x & 7;
  const int m = blockIdx.x >> 3;
  const int kc = tid & 31;
  const int rg = tid >> 5;
  const int row0 = m*32 + rg*4;
  const int REPSTRIDE = 2*NB*HD;             // floats between replicas

  for (int i = tid; i < 4096; i += 256) xs[i] = x[g*4096 + i];

  // Wh fragments: 4 rows x 32 k (8 float4), k-rotated to spread LDS banks
  float4 wv[4][8];
#pragma unroll
  for (int r = 0; r < 4; ++r)
#pragma unroll
    for (int j = 0; j < 8; ++j)
      wv[r][j] = *reinterpret_cast<const float4*>(
          whw + (size_t)(row0 + r)*HD + kc*32 + ((4*(j + kc)) & 31));

  // lane kc<16 of each rg writes (row rr, batch bb)
  const int rr = row0 + (kc & 3);
  const int bb = kc >> 2;
  const float bias = whb[rr];
  unsigned int* bar = cnt + g*32;            // 128B-padded per-group counter
  __syncthreads();                           // xs ready

  // prefetch XW operand for t=0
  float xwv = 0.f;
  if (kc < 16) xwv = XW[(size_t)xs[bb*1024]*HD + rr];

  for (int t = 0; t < NS; ++t){
    const float* hin = hstate + (size_t)(m & 1)*REPSTRIDE
                     + (size_t)(t & 1)*(NB*HD) + g*4*HD;
    // stage 4 batch rows of h (16 KB) straight from IC via 8B atomic loads
    const unsigned long long* h64 = reinterpret_cast<const unsigned long long*>(hin);
#pragma unroll
    for (int q = 0; q < 4; ++q){
      unsigned long long v0 = __hip_atomic_load(h64 + q*512 + tid*2,
          __ATOMIC_RELAXED, __HIP_MEMORY_SCOPE_AGENT);
      unsigned long long v1 = __hip_atomic_load(h64 + q*512 + tid*2 + 1,
          __ATOMIC_RELAXED, __HIP_MEMORY_SCOPE_AGENT);
      const float2 f0 = __builtin_bit_cast(float2, v0);
      const float2 f1 = __builtin_bit_cast(float2, v1);
      *reinterpret_cast<float4*>(&hs[q*1024 + tid*4]) = float4{f0.x, f0.y, f1.x, f1.y};
    }
    __syncthreads();

    float acc[4][4] = {};   // [row r][batch b]
#pragma unroll
    for (int j = 0; j < 8; ++j){
      const int off = kc*32 + ((4*(j + kc)) & 31);
      float4 h4[4];
#pragma unroll
      for (int b = 0; b < 4; ++b)
        h4[b] = *reinterpret_cast<const float4*>(&hs[b*1024 + off]);
#pragma unroll
      for (int r = 0; r < 4; ++r)
#pragma unroll
        for (int b = 0; b < 4; ++b)
          acc[r][b] += wv[r][j].x*h4[b].x + wv[r][j].y*h4[b].y
                     + wv[r][j].z*h4[b].z + wv[r][j].w*h4[b].w;
    }
    // butterfly reduce across the 32 kc-lanes (stays within each 32-lane half)
#pragma unroll
    for (int mm = 1; mm <= 16; mm <<= 1)
#pragma unroll
      for (int r = 0; r < 4; ++r)
#pragma unroll
        for (int b = 0; b < 4; ++b)
          acc[r][b] += __shfl_xor(acc[r][b], mm);
    // all lanes hold all 16 totals; lane kc<16 takes acc[kc&3][kc>>2]
    float sv = acc[0][0];
#pragma unroll
    for (int r = 0; r < 4; ++r)
#pragma unroll
      for (int b = 0; b < 4; ++b)
        if ((kc & 15) == b*4 + r) sv = acc[r][b];

    if (kc < 16){
      const float val = tanhf(xwv + bias + sv);
      float* hout = hstate + (size_t)((t & 1)^1)*(NB*HD) + g*4*HD + bb*HD + rr;
      // write-through stores to BOTH replicas (parallel, same RT)
      __hip_atomic_store(hout, val, __ATOMIC_RELAXED, __HIP_MEMORY_SCOPE_AGENT);
      __hip_atomic_store(hout + REPSTRIDE, val, __ATOMIC_RELAXED,
                         __HIP_MEMORY_SCOPE_AGENT);
      Harc[(((size_t)(g*4 + bb))*NS + t)*HD + rr] = f2bf(val);
    }
    // prefetch XW operand for t+1 (read-only; overlaps the drain/flag/poll)
    float xwv_next = 0.f;
    if (kc < 16 && t + 1 < NS) xwv_next = XW[(size_t)xs[bb*1024 + t + 1]*HD + rr];
    __syncthreads();   // per-wave vmcnt(0) before s_barrier: stores IC-visible
    if (tid == 0){
      __hip_atomic_fetch_add(bar, 1u, __ATOMIC_RELAXED, __HIP_MEMORY_SCOPE_AGENT);
      const unsigned int target = 32u*(unsigned)(t+1);
      while (__hip_atomic_load(bar, __ATOMIC_RELAXED, __HIP_MEMORY_SCOPE_AGENT) < target)
        __builtin_amdgcn_s_sleep(1);
      // no fence: h is read IC-coherently; all other scan inputs are read-only
    }
    __syncthreads();
    xwv = xwv_next;
  }
}

// ---------------- K3: A = H @ Wa^T + b  (MFMA, 128x128 tile) ----------------
__global__ __launch_bounds__(256) void k_gemm_A(const u16* __restrict__ Harc,
    const u16* __restrict__ wa_bf, const float* __restrict__ wab,
    u16* __restrict__ Aarc)
{
  __shared__ u16 As[128][40];
  __shared__ u16 Bs[128][40];
  const int tid = threadIdx.x;
  const int m0 = blockIdx.x * 128;
  const int n0 = blockIdx.y * 128;
  const int l = tid & 63, w = tid >> 6;
  const int wr = w >> 1, wc = w & 1;
  const int lr = l & 15, lg = l >> 4;
  const int srow = tid >> 1, shalf = (tid & 1) * 16;
  f32x4 acc[4][4] = {};
  for (int k0 = 0; k0 < 1024; k0 += 32){
    {
      const u16* a = Harc + (size_t)(m0 + srow)*HD + k0 + shalf;
      ushort8 a0 = *(const ushort8*)a, a1 = *(const ushort8*)(a+8);
      const u16* b = wa_bf + (size_t)(n0 + srow)*HD + k0 + shalf;
      ushort8 b0 = *(const ushort8*)b, b1 = *(const ushort8*)(b+8);
      *(ushort8*)&As[srow][shalf] = a0; *(ushort8*)&As[srow][shalf+8] = a1;
      *(ushort8*)&Bs[srow][shalf] = b0; *(ushort8*)&Bs[srow][shalf+8] = b1;
    }
    __syncthreads();
    bf16x8 af[4], bfr[4];
#pragma unroll
    for (int i = 0; i < 4; ++i){
      af[i]  = *(const bf16x8*)&As[wr*64 + i*16 + lr][lg*8];
      bfr[i] = *(const bf16x8*)&Bs[wc*64 + i*16 + lr][lg*8];
    }
#pragma unroll
    for (int i = 0; i < 4; ++i)
#pragma unroll
      for (int j = 0; j < 4; ++j)
        acc[i][j] = MFMA16(af[i], bfr[j], acc[i][j]);
    __syncthreads();
  }
#pragma unroll
  for (int i = 0; i < 4; ++i){
    const int row = m0 + wr*64 + i*16 + lg*4;
#pragma unroll
    for (int j = 0; j < 4; ++j){
      const int col = n0 + wc*64 + j*16 + lr;
      const float bias = wab[col];
#pragma unroll
      for (int r = 0; r < 4; ++r)
        Aarc[(size_t)(row + r)*HD + col] = f2bf(acc[i][j][r] + bias);
    }
  }
}

// ---------------- K4a: S[b,t,s] = H[b,t]·A[b,s]  (causal tiles only) ----------------
__global__ __launch_bounds__(256) void k_scores(const u16* __restrict__ Harc,
    const u16* __restrict__ Aarc, u16* __restrict__ SW)
{
  if (blockIdx.x > blockIdx.y) return;   // s-tile beyond t-tile: never read
  __shared__ u16 As[128][40];
  __shared__ u16 Bs[128][40];
  const int tid = threadIdx.x;
  const int bz = blockIdx.z;
  const int m0 = blockIdx.y * 128;   // t
  const int n0 = blockIdx.x * 128;   // s
  const u16* Hb = Harc + (size_t)bz * NS * HD;
  const u16* Ab = Aarc + (size_t)bz * NS * HD;
  u16* Sb = SW + ((size_t)bz << 20);
  const int l = tid & 63, w = tid >> 6;
  const int wr = w >> 1, wc = w & 1;
  const int lr = l & 15, lg = l >> 4;
  const int srow = tid >> 1, shalf = (tid & 1) * 16;
  f32x4 acc[4][4] = {};
  for (int k0 = 0; k0 < 1024; k0 += 32){
    {
      const u16* a = Hb + (size_t)(m0 + srow)*HD + k0 + shalf;
      ushort8 a0 = *(const ushort8*)a, a1 = *(const ushort8*)(a+8);
      const u16* b = Ab + (size_t)(n0 + srow)*HD + k0 + shalf;
      ushort8 b0 = *(const ushort8*)b, b1 = *(const ushort8*)(b+8);
      *(ushort8*)&As[srow][shalf] = a0; *(ushort8*)&As[srow][shalf+8] = a1;
      *(ushort8*)&Bs[srow][shalf] = b0; *(ushort8*)&Bs[srow][shalf+8] = b1;
    }
    __syncthreads();
    bf16x8 af[4], bfr[4];
#pragma unroll
    for (int i = 0; i < 4; ++i){
      af[i]  = *(const bf16x8*)&As[wr*64 + i*16 + lr][lg*8];
      bfr[i] = *(const bf16x8*)&Bs[wc*64 + i*16 + lr][lg*8];
    }
#pragma unroll
    for (int i = 0; i < 4; ++i)
#pragma unroll
      for (int j = 0; j < 4; ++j)
        acc[i][j] = MFMA16(af[i], bfr[j], acc[i][j]);
    __syncthreads();
  }
#pragma unroll
  for (int i = 0; i < 4; ++i){
    const int row = m0 + wr*64 + i*16 + lg*4;
#pragma unroll
    for (int j = 0; j < 4; ++j){
      const int col = n0 + wc*64 + j*16 + lr;
#pragma unroll
      for (int r = 0; r < 4; ++r)
        Sb[((size_t)(row + r) << 10) + col] = f2bf(acc[i][j][r]);
    }
  }
}

// ---------------- K4b: row softmax over s (in place, zero-fill s>t) ----------------
__global__ __launch_bounds__(256) void k_softmax(u16* __restrict__ SW)
{
  const int bid = blockIdx.x;
  const int b = bid >> 10, t = bid & 1023;
  u16* row = SW + ((size_t)b << 20) + ((size_t)t << 10);
  const int i0 = threadIdx.x * 4;
  u16x4 v = *(const u16x4*)(row + i0);
  float x[4];
#pragma unroll
  for (int j = 0; j < 4; ++j) x[j] = (i0 + j <= t) ? bf2f(v[j]) : -1e30f;
  float m = fmaxf(fmaxf(x[0], x[1]), fmaxf(x[2], x[3]));
#pragma unroll
  for (int o = 1; o < 64; o <<= 1) m = fmaxf(m, __shfl_xor(m, o));
  __shared__ float redm[4], reds[4];
  if ((threadIdx.x & 63) == 0) redm[threadIdx.x >> 6] = m;
  __syncthreads();
  m = fmaxf(fmaxf(redm[0], redm[1]), fmaxf(redm[2], redm[3]));
  float e[4]; float s = 0.f;
#pragma unroll
  for (int j = 0; j < 4; ++j){ e[j] = __expf(x[j] - m); s += e[j]; }
#pragma unroll
  for (int o = 1; o < 64; o <<= 1) s += __shfl_xor(s, o);
  if ((threadIdx.x & 63) == 0) reds[threadIdx.x >> 6] = s;
  __syncthreads();
  s = reds[0] + reds[1] + reds[2] + reds[3];
  const float inv = 1.f / s;
  u16x4 o4;
#pragma unroll
  for (int j = 0; j < 4; ++j) o4[j] = f2bf(e[j] * inv);
  *(u16x4*)(row + i0) = o4;
}

// ---------------- K4c: Ctx[b,t,e] = sum_s W[b,t,s] * H[b,s,e] ----------------
__global__ __launch_bounds__(256) void k_pv(const u16* __restrict__ SW,
    const u16* __restrict__ Harc, u16* __restrict__ Ctx)
{
  __shared__ u16 As[128][40];   // W rows t, cols s
  __shared__ u16 Bs[128][40];   // H^T rows e, cols s
  const int tid = threadIdx.x;
  const int bz = blockIdx.z;
  const int t0 = blockIdx.x * 128;
  const int e0 = blockIdx.y * 128;
  const u16* Wb = SW + ((size_t)bz << 20);
  const u16* Hb = Harc + (size_t)bz * NS * HD;
  u16* Cb = Ctx + (size_t)bz * NS * HD;
  const int l = tid & 63, w = tid >> 6;
  const int wr = w >> 1, wc = w & 1;
  const int lr = l & 15, lg = l >> 4;
  const int srow = tid >> 1, shalf = (tid & 1) * 16;
  const int sIdx = tid & 31, ec = tid >> 5;
  const int ksteps = (blockIdx.x + 1) * 4;    // s < t0 + 128 (causal bound)
  f32x4 acc[4][4] = {};
  for (int ks = 0; ks < ksteps; ++ks){
    const int k0 = ks * 32;
    {
      const u16* a = Wb + ((size_t)(t0 + srow) << 10) + k0 + shalf;
      ushort8 a0 = *(const ushort8*)a, a1 = *(const ushort8*)(a+8);
      const u16* b = Hb + (size_t)(k0 + sIdx)*HD + e0 + ec*16;
      ushort8 b0 = *(const ushort8*)b, b1 = *(const ushort8*)(b+8);
      *(ushort8*)&As[srow][shalf] = a0; *(ushort8*)&As[srow][shalf+8] = a1;
#pragma unroll
      for (int i = 0; i < 8; ++i){
        Bs[ec*16 + i][sIdx] = b0[i];
        Bs[ec*16 + 8 + i][sIdx] = b1[i];
      }
    }
    __syncthreads();
    bf16x8 af[4], bfr[4];
#pragma unroll
    for (int i = 0; i < 4; ++i){
      af[i]  = *(const bf16x8*)&As[wr*64 + i*16 + lr][lg*8];
      bfr[i] = *(const bf16x8*)&Bs[wc*64 + i*16 + lr][lg*8];
    }
#pragma unroll
    for (int i = 0; i < 4; ++i)
#pragma unroll
      for (int j = 0; j < 4; ++j)
        acc[i][j] = MFMA16(af[i], bfr[j], acc[i][j]);
    __syncthreads();
  }
#pragma unroll
  for (int i = 0; i < 4; ++i){
    const int row = t0 + wr*64 + i*16 + lg*4;
#pragma unroll
    for (int j = 0; j < 4; ++j){
      const int col = e0 + wc*64 + j*16 + lr;
#pragma unroll
      for (int r = 0; r < 4; ++r)
        Cb[(size_t)(row + r)*HD + col] = f2bf(acc[i][j][r]);
    }
  }
}

// ---------------- K5: out = [H|ctx] @ fc^T + b  (MFMA, N=128) ----------------
__global__ __launch_bounds__(256) void k_out2(const u16* __restrict__ Harc,
    const u16* __restrict__ Ctx, const u16* __restrict__ fc_bf,
    const float* __restrict__ fcb, float* __restrict__ out)
{
  __shared__ u16 As[128][40];
  __shared__ u16 Bs[128][40];
  const int tid = threadIdx.x;
  const int m0 = blockIdx.x * 128;
  const int l = tid & 63, w = tid >> 6;
  const int wr = w >> 1, wc = w & 1;
  const int lr = l & 15, lg = l >> 4;
  const int srow = tid >> 1, shalf = (tid & 1) * 16;
  f32x4 acc[4][4] = {};
  for (int k0 = 0; k0 < 2048; k0 += 32){
    {
      const u16* abase = (k0 < 1024) ? Harc : Ctx;
      const u16* a = abase + (size_t)(m0 + srow)*HD + (k0 & 1023) + shalf;
      ushort8 a0 = *(const ushort8*)a, a1 = *(const ushort8*)(a+8);
      const u16* b = fc_bf + (size_t)srow*2048 + k0 + shalf;
      ushort8 b0 = *(const ushort8*)b, b1 = *(const ushort8*)(b+8);
      *(ushort8*)&As[srow][shalf] = a0; *(ushort8*)&As[srow][shalf+8] = a1;
      *(ushort8*)&Bs[srow][shalf] = b0; *(ushort8*)&Bs[srow][shalf+8] = b1;
    }
    __syncthreads();
    bf16x8 af[4], bfr[4];
#pragma unroll
    for (int i = 0; i < 4; ++i){
      af[i]  = *(const bf16x8*)&As[wr*64 + i*16 + lr][lg*8];
      bfr[i] = *(const bf16x8*)&Bs[wc*64 + i*16 + lr][lg*8];
    }
#pragma unroll
    for (int i = 0; i < 4; ++i)
#pragma unroll
      for (int j = 0; j < 4; ++j)
        acc[i][j] = MFMA16(af[i], bfr[j], acc[i][j]);
    __syncthreads();
  }
#pragma unroll
  for (int i = 0; i < 4; ++i){
    const int row = m0 + wr*64 + i*16 + lg*4;
#pragma unroll
    for (int j = 0; j < 4; ++j){
      const int col = wc*64 + j*16 + lr;
      const float bias = fcb[col];
#pragma unroll
      for (int r = 0; r < 4; ++r)
        out[(size_t)(row + r)*NV + col] = acc[i][j][r] + bias;
    }
  }
}

extern "C" void kernel_launch(void* const* d_in, const int* in_sizes, int n_in,
                              void* d_out, int out_size, void* d_ws, size_t ws_size,
                              hipStream_t stream)
{
  const int*   x   = (const int*)  d_in[0];
  const float* emb = (const float*)d_in[1];
  const float* wxw = (const float*)d_in[2];
  const float* wxb = (const float*)d_in[3];
  const float* whw = (const float*)d_in[4];
  const float* whb = (const float*)d_in[5];
  const float* waw = (const float*)d_in[6];
  const float* wab = (const float*)d_in[7];
  const float* fcw = (const float*)d_in[8];
  const float* fcb = (const float*)d_in[9];
  float* out = (float*)d_out;

  char* ws = (char*)d_ws;
  unsigned int* cnt = (unsigned int*)(ws);            // 4 KB
  float* hstate = (float*)(ws + 4096);                // 512 KB (2 replicas x 2 pingpong x 128KB)
  float* XW     = (float*)(ws + 528384);              // 512 KB
  u16*   Harc   = (u16*)  (ws + 1052672);             // 64 MB  H archive (bf16)
  u16*   Aarc   = (u16*)  (ws + 68161536);            // 64 MB  A archive; later reused as Ctx
  u16*   SW     = (u16*)  (ws + 135270400);           // 64 MB  scores/weights (in place)
  u16*   wa_bf  = (u16*)  (ws + 135270400);           // aliases SW (dead before scores)
  u16*   fc_bf  = (u16*)  (ws + 202379264);           // 512 KB -> total ~202.9 MB
  u16*   Ctx    = Aarc;                               // PV output overwrites A archive

  (void)hipMemsetAsync(ws, 0, 528384, stream);        // cnt + both hstate replicas

  k_cvt<<<dim3(5120), dim3(256), 0, stream>>>(waw, fcw, wa_bf, fc_bf);
  k_xw<<<dim3(NV), dim3(256), 0, stream>>>(emb, wxw, wxb, XW);

  {
    void* args[] = { (void*)&x, (void*)&whw, (void*)&whb, (void*)&XW,
                     (void*)&hstate, (void*)&Harc, (void*)&cnt };
    (void)hipLaunchCooperativeKernel((const void*)k_scan2, dim3(256), dim3(256),
                                     args, 0, stream);
  }

  k_gemm_A<<<dim3(256, 8), dim3(256), 0, stream>>>(Harc, wa_bf, wab, Aarc);
  k_scores<<<dim3(8, 8, 32), dim3(256), 0, stream>>>(Harc, Aarc, SW);
  k_softmax<<<dim3(32768), dim3(256), 0, stream>>>(SW);
  k_pv<<<dim3(8, 8, 32), dim3(256), 0, stream>>>(SW, Harc, Ctx);
  k_out2<<<dim3(256), dim3(256), 0, stream>>>(Harc, Ctx, fc_bf, fcb, out);
}

// Round 13
// 5081.381 us; speedup vs baseline: 1.0915x; 1.0915x over previous
//
#include <hip/hip_runtime.h>
#include <hip/hip_bf16.h>
#include <hip/hip_cooperative_groups.h>

#define NV 128
#define NE 256
#define HD 1024
#define NB 32
#define NS 1024

typedef unsigned short u16;
typedef unsigned short ushort8 __attribute__((ext_vector_type(8)));
typedef unsigned short u16x4 __attribute__((ext_vector_type(4)));
typedef short bf16x8 __attribute__((ext_vector_type(8)));
typedef float f32x4 __attribute__((ext_vector_type(4)));

#define MFMA16(a, b, c) __builtin_amdgcn_mfma_f32_16x16x32_bf16(a, b, c, 0, 0, 0)

__device__ __forceinline__ float bf2f(u16 u){
  unsigned int x = ((unsigned int)u) << 16;
  return __builtin_bit_cast(float, x);
}
__device__ __forceinline__ u16 f2bf(float f){
  unsigned int u = __builtin_bit_cast(unsigned int, f);
  unsigned int r = u + 0x7fffu + ((u >> 16) & 1u);
  return (u16)(r >> 16);
}

// ---------------- K0: fp32 weights -> bf16 copies ----------------
__global__ __launch_bounds__(256) void k_cvt(const float* __restrict__ waw,
    const float* __restrict__ fcw, u16* __restrict__ wa_bf, u16* __restrict__ fc_bf)
{
  const int i = blockIdx.x * 256 + threadIdx.x;
  if (i < 1048576) wa_bf[i] = f2bf(waw[i]);
  const int j = i - 1048576;
  if (j >= 0 && j < 262144) fc_bf[j] = f2bf(fcw[j]);
}

// ---------------- K1: XW[v,h] = sum_e emb[v,e]*Wx[h,e] + Wx_b[h] ----------------
__global__ __launch_bounds__(256) void k_xw(const float* __restrict__ emb,
    const float* __restrict__ wxw, const float* __restrict__ wxb,
    float* __restrict__ XW)
{
  __shared__ float es[NE];
  const int v = blockIdx.x;
  for (int i = threadIdx.x; i < NE; i += 256) es[i] = emb[v*NE + i];
  __syncthreads();
  for (int h = threadIdx.x; h < HD; h += 256){
    const float* wr = wxw + (size_t)h * NE;
    float acc = 0.f;
#pragma unroll 4
    for (int e = 0; e < NE; e += 4){
      float4 w4 = *reinterpret_cast<const float4*>(wr + e);
      acc += w4.x*es[e] + w4.y*es[e+1] + w4.z*es[e+2] + w4.w*es[e+3];
    }
    XW[(size_t)v*HD + h] = acc + wxb[h];
  }
}

// ---------------- K2: RNN scan (R11 + slot barrier: no RMW serialization) -------
// 256 WGs x 256 thr, 8 groups of 32 WGs; group g = bid&7 owns batches 4g..4g+3.
// R=4 rows x K=32 tiling (kc = tid&31, rg = tid>>5). Fence-free IC exchange
// (R11-proven). NEW (isolated change): barrier arrival = per-WG slot store
// (32 parallel stores, distinct 128B lines — replaces 32 serialized fetch_adds
// on one line); departure = 32 lanes of wave 0 poll all slots in parallel.
__global__ __launch_bounds__(256, 2) void k_scan2(const int* __restrict__ x,
    const float* __restrict__ whw, const float* __restrict__ whb,
    const float* __restrict__ XW, float* __restrict__ hstate,
    u16* __restrict__ Harc, unsigned int* __restrict__ cnt)
{
  __shared__ __align__(16) float hs[4096];   // 4 batches x 1024
  __shared__ int xs[4096];                   // 4 batches x 1024 token ids
  const int tid = threadIdx.x;
  const int g = blockIdx.x & 7;
  const int m = blockIdx.x >> 3;
  const int kc = tid & 31;
  const int rg = tid >> 5;
  const int row0 = m*32 + rg*4;

  for (int i = tid; i < 4096; i += 256) xs[i] = x[g*4096 + i];

  // Wh fragments: 4 rows x 32 k (8 float4), k-rotated to spread LDS banks
  float4 wv[4][8];
#pragma unroll
  for (int r = 0; r < 4; ++r)
#pragma unroll
    for (int j = 0; j < 8; ++j)
      wv[r][j] = *reinterpret_cast<const float4*>(
          whw + (size_t)(row0 + r)*HD + kc*32 + ((4*(j + kc)) & 31));

  // lane kc<16 of each rg writes (row rr, batch bb)
  const int rr = row0 + (kc & 3);
  const int bb = kc >> 2;
  const float bias = whb[rr];
  unsigned int* slots = cnt + g*1024;        // 32 slots, 128B apart (idx m*32)
  __syncthreads();                           // xs ready

  for (int t = 0; t < NS; ++t){
    const float* hin  = hstate + (size_t)(t & 1)*(NB*HD) + g*4*HD;
    float*       hout = hstate + (size_t)((t & 1)^1)*(NB*HD) + g*4*HD;
    // stage 4 batch rows of h (16 KB) straight from IC via 8B atomic loads
    const unsigned long long* h64 = reinterpret_cast<const unsigned long long*>(hin);
#pragma unroll
    for (int q = 0; q < 4; ++q){
      unsigned long long v0 = __hip_atomic_load(h64 + q*512 + tid*2,
          __ATOMIC_RELAXED, __HIP_MEMORY_SCOPE_AGENT);
      unsigned long long v1 = __hip_atomic_load(h64 + q*512 + tid*2 + 1,
          __ATOMIC_RELAXED, __HIP_MEMORY_SCOPE_AGENT);
      const float2 f0 = __builtin_bit_cast(float2, v0);
      const float2 f1 = __builtin_bit_cast(float2, v1);
      *reinterpret_cast<float4*>(&hs[q*1024 + tid*4]) = float4{f0.x, f0.y, f1.x, f1.y};
    }
    // per-step gather operand (L1/L2-warm since no fence invalidates)
    float xwv = 0.f;
    if (kc < 16){
      const int xv = xs[bb*1024 + t];
      xwv = XW[(size_t)xv*HD + rr];
    }
    __syncthreads();

    float acc[4][4] = {};   // [row r][batch b]
#pragma unroll
    for (int j = 0; j < 8; ++j){
      const int off = kc*32 + ((4*(j + kc)) & 31);
      float4 h4[4];
#pragma unroll
      for (int b = 0; b < 4; ++b)
        h4[b] = *reinterpret_cast<const float4*>(&hs[b*1024 + off]);
#pragma unroll
      for (int r = 0; r < 4; ++r)
#pragma unroll
        for (int b = 0; b < 4; ++b)
          acc[r][b] += wv[r][j].x*h4[b].x + wv[r][j].y*h4[b].y
                     + wv[r][j].z*h4[b].z + wv[r][j].w*h4[b].w;
    }
    // butterfly reduce across the 32 kc-lanes (stays within each 32-lane half)
#pragma unroll
    for (int mm = 1; mm <= 16; mm <<= 1)
#pragma unroll
      for (int r = 0; r < 4; ++r)
#pragma unroll
        for (int b = 0; b < 4; ++b)
          acc[r][b] += __shfl_xor(acc[r][b], mm);
    // all lanes hold all 16 totals; lane kc<16 takes acc[kc&3][kc>>2]
    float sv = acc[0][0];
#pragma unroll
    for (int r = 0; r < 4; ++r)
#pragma unroll
      for (int b = 0; b < 4; ++b)
        if ((kc & 15) == b*4 + r) sv = acc[r][b];

    if (kc < 16){
      const float val = tanhf(xwv + bias + sv);
      // write-through store: at IC once vmcnt drains (next __syncthreads)
      __hip_atomic_store(&hout[bb*HD + rr], val, __ATOMIC_RELAXED,
                         __HIP_MEMORY_SCOPE_AGENT);
      Harc[(((size_t)(g*4 + bb))*NS + t)*HD + rr] = f2bf(val);
    }
    __syncthreads();   // per-wave vmcnt(0) before s_barrier: stores IC-visible
    // arrival: one parallel slot store per WG (no RMW chain)
    if (tid == 0)
      __hip_atomic_store(&slots[m*32], (unsigned)(t + 1), __ATOMIC_RELAXED,
                         __HIP_MEMORY_SCOPE_AGENT);
    // departure: lanes 0..31 of wave 0 poll all 32 slots in parallel
    if (tid < 64){
      const unsigned tgt = (unsigned)(t + 1);
      while (true){
        unsigned v = (tid < 32)
          ? __hip_atomic_load(&slots[tid*32], __ATOMIC_RELAXED,
                              __HIP_MEMORY_SCOPE_AGENT)
          : tgt;
        if (__all(v >= tgt)) break;
        __builtin_amdgcn_s_sleep(1);
      }
      // no fence: h is read IC-coherently; other scan inputs are read-only
    }
    __syncthreads();
  }
}

// ---------------- K3: A = H @ Wa^T + b  (MFMA, 128x128 tile) ----------------
__global__ __launch_bounds__(256) void k_gemm_A(const u16* __restrict__ Harc,
    const u16* __restrict__ wa_bf, const float* __restrict__ wab,
    u16* __restrict__ Aarc)
{
  __shared__ u16 As[128][40];
  __shared__ u16 Bs[128][40];
  const int tid = threadIdx.x;
  const int m0 = blockIdx.x * 128;
  const int n0 = blockIdx.y * 128;
  const int l = tid & 63, w = tid >> 6;
  const int wr = w >> 1, wc = w & 1;
  const int lr = l & 15, lg = l >> 4;
  const int srow = tid >> 1, shalf = (tid & 1) * 16;
  f32x4 acc[4][4] = {};
  for (int k0 = 0; k0 < 1024; k0 += 32){
    {
      const u16* a = Harc + (size_t)(m0 + srow)*HD + k0 + shalf;
      ushort8 a0 = *(const ushort8*)a, a1 = *(const ushort8*)(a+8);
      const u16* b = wa_bf + (size_t)(n0 + srow)*HD + k0 + shalf;
      ushort8 b0 = *(const ushort8*)b, b1 = *(const ushort8*)(b+8);
      *(ushort8*)&As[srow][shalf] = a0; *(ushort8*)&As[srow][shalf+8] = a1;
      *(ushort8*)&Bs[srow][shalf] = b0; *(ushort8*)&Bs[srow][shalf+8] = b1;
    }
    __syncthreads();
    bf16x8 af[4], bfr[4];
#pragma unroll
    for (int i = 0; i < 4; ++i){
      af[i]  = *(const bf16x8*)&As[wr*64 + i*16 + lr][lg*8];
      bfr[i] = *(const bf16x8*)&Bs[wc*64 + i*16 + lr][lg*8];
    }
#pragma unroll
    for (int i = 0; i < 4; ++i)
#pragma unroll
      for (int j = 0; j < 4; ++j)
        acc[i][j] = MFMA16(af[i], bfr[j], acc[i][j]);
    __syncthreads();
  }
#pragma unroll
  for (int i = 0; i < 4; ++i){
    const int row = m0 + wr*64 + i*16 + lg*4;
#pragma unroll
    for (int j = 0; j < 4; ++j){
      const int col = n0 + wc*64 + j*16 + lr;
      const float bias = wab[col];
#pragma unroll
      for (int r = 0; r < 4; ++r)
        Aarc[(size_t)(row + r)*HD + col] = f2bf(acc[i][j][r] + bias);
    }
  }
}

// ---------------- K4a: S[b,t,s] = H[b,t]·A[b,s]  (causal tiles only) ----------------
__global__ __launch_bounds__(256) void k_scores(const u16* __restrict__ Harc,
    const u16* __restrict__ Aarc, u16* __restrict__ SW)
{
  if (blockIdx.x > blockIdx.y) return;   // s-tile beyond t-tile: never read
  __shared__ u16 As[128][40];
  __shared__ u16 Bs[128][40];
  const int tid = threadIdx.x;
  const int bz = blockIdx.z;
  const int m0 = blockIdx.y * 128;   // t
  const int n0 = blockIdx.x * 128;   // s
  const u16* Hb = Harc + (size_t)bz * NS * HD;
  const u16* Ab = Aarc + (size_t)bz * NS * HD;
  u16* Sb = SW + ((size_t)bz << 20);
  const int l = tid & 63, w = tid >> 6;
  const int wr = w >> 1, wc = w & 1;
  const int lr = l & 15, lg = l >> 4;
  const int srow = tid >> 1, shalf = (tid & 1) * 16;
  f32x4 acc[4][4] = {};
  for (int k0 = 0; k0 < 1024; k0 += 32){
    {
      const u16* a = Hb + (size_t)(m0 + srow)*HD + k0 + shalf;
      ushort8 a0 = *(const ushort8*)a, a1 = *(const ushort8*)(a+8);
      const u16* b = Ab + (size_t)(n0 + srow)*HD + k0 + shalf;
      ushort8 b0 = *(const ushort8*)b, b1 = *(const ushort8*)(b+8);
      *(ushort8*)&As[srow][shalf] = a0; *(ushort8*)&As[srow][shalf+8] = a1;
      *(ushort8*)&Bs[srow][shalf] = b0; *(ushort8*)&Bs[srow][shalf+8] = b1;
    }
    __syncthreads();
    bf16x8 af[4], bfr[4];
#pragma unroll
    for (int i = 0; i < 4; ++i){
      af[i]  = *(const bf16x8*)&As[wr*64 + i*16 + lr][lg*8];
      bfr[i] = *(const bf16x8*)&Bs[wc*64 + i*16 + lr][lg*8];
    }
#pragma unroll
    for (int i = 0; i < 4; ++i)
#pragma unroll
      for (int j = 0; j < 4; ++j)
        acc[i][j] = MFMA16(af[i], bfr[j], acc[i][j]);
    __syncthreads();
  }
#pragma unroll
  for (int i = 0; i < 4; ++i){
    const int row = m0 + wr*64 + i*16 + lg*4;
#pragma unroll
    for (int j = 0; j < 4; ++j){
      const int col = n0 + wc*64 + j*16 + lr;
#pragma unroll
      for (int r = 0; r < 4; ++r)
        Sb[((size_t)(row + r) << 10) + col] = f2bf(acc[i][j][r]);
    }
  }
}

// ---------------- K4b: row softmax over s (in place, zero-fill s>t) ----------------
__global__ __launch_bounds__(256) void k_softmax(u16* __restrict__ SW)
{
  const int bid = blockIdx.x;
  const int b = bid >> 10, t = bid & 1023;
  u16* row = SW + ((size_t)b << 20) + ((size_t)t << 10);
  const int i0 = threadIdx.x * 4;
  u16x4 v = *(const u16x4*)(row + i0);
  float x[4];
#pragma unroll
  for (int j = 0; j < 4; ++j) x[j] = (i0 + j <= t) ? bf2f(v[j]) : -1e30f;
  float m = fmaxf(fmaxf(x[0], x[1]), fmaxf(x[2], x[3]));
#pragma unroll
  for (int o = 1; o < 64; o <<= 1) m = fmaxf(m, __shfl_xor(m, o));
  __shared__ float redm[4], reds[4];
  if ((threadIdx.x & 63) == 0) redm[threadIdx.x >> 6] = m;
  __syncthreads();
  m = fmaxf(fmaxf(redm[0], redm[1]), fmaxf(redm[2], redm[3]));
  float e[4]; float s = 0.f;
#pragma unroll
  for (int j = 0; j < 4; ++j){ e[j] = __expf(x[j] - m); s += e[j]; }
#pragma unroll
  for (int o = 1; o < 64; o <<= 1) s += __shfl_xor(s, o);
  if ((threadIdx.x & 63) == 0) reds[threadIdx.x >> 6] = s;
  __syncthreads();
  s = reds[0] + reds[1] + reds[2] + reds[3];
  const float inv = 1.f / s;
  u16x4 o4;
#pragma unroll
  for (int j = 0; j < 4; ++j) o4[j] = f2bf(e[j] * inv);
  *(u16x4*)(row + i0) = o4;
}

// ---------------- K4c: Ctx[b,t,e] = sum_s W[b,t,s] * H[b,s,e] ----------------
__global__ __launch_bounds__(256) void k_pv(const u16* __restrict__ SW,
    const u16* __restrict__ Harc, u16* __restrict__ Ctx)
{
  __shared__ u16 As[128][40];   // W rows t, cols s
  __shared__ u16 Bs[128][40];   // H^T rows e, cols s
  const int tid = threadIdx.x;
  const int bz = blockIdx.z;
  const int t0 = blockIdx.x * 128;
  const int e0 = blockIdx.y * 128;
  const u16* Wb = SW + ((size_t)bz << 20);
  const u16* Hb = Harc + (size_t)bz * NS * HD;
  u16* Cb = Ctx + (size_t)bz * NS * HD;
  const int l = tid & 63, w = tid >> 6;
  const int wr = w >> 1, wc = w & 1;
  const int lr = l & 15, lg = l >> 4;
  const int srow = tid >> 1, shalf = (tid & 1) * 16;
  const int sIdx = tid & 31, ec = tid >> 5;
  const int ksteps = (blockIdx.x + 1) * 4;    // s < t0 + 128 (causal bound)
  f32x4 acc[4][4] = {};
  for (int ks = 0; ks < ksteps; ++ks){
    const int k0 = ks * 32;
    {
      const u16* a = Wb + ((size_t)(t0 + srow) << 10) + k0 + shalf;
      ushort8 a0 = *(const ushort8*)a, a1 = *(const ushort8*)(a+8);
      const u16* b = Hb + (size_t)(k0 + sIdx)*HD + e0 + ec*16;
      ushort8 b0 = *(const ushort8*)b, b1 = *(const ushort8*)(b+8);
      *(ushort8*)&As[srow][shalf] = a0; *(ushort8*)&As[srow][shalf+8] = a1;
#pragma unroll
      for (int i = 0; i < 8; ++i){
        Bs[ec*16 + i][sIdx] = b0[i];
        Bs[ec*16 + 8 + i][sIdx] = b1[i];
      }
    }
    __syncthreads();
    bf16x8 af[4], bfr[4];
#pragma unroll
    for (int i = 0; i < 4; ++i){
      af[i]  = *(const bf16x8*)&As[wr*64 + i*16 + lr][lg*8];
      bfr[i] = *(const bf16x8*)&Bs[wc*64 + i*16 + lr][lg*8];
    }
#pragma unroll
    for (int i = 0; i < 4; ++i)
#pragma unroll
      for (int j = 0; j < 4; ++j)
        acc[i][j] = MFMA16(af[i], bfr[j], acc[i][j]);
    __syncthreads();
  }
#pragma unroll
  for (int i = 0; i < 4; ++i){
    const int row = t0 + wr*64 + i*16 + lg*4;
#pragma unroll
    for (int j = 0; j < 4; ++j){
      const int col = e0 + wc*64 + j*16 + lr;
#pragma unroll
      for (int r = 0; r < 4; ++r)
        Cb[(size_t)(row + r)*HD + col] = f2bf(acc[i][j][r]);
    }
  }
}

// ---------------- K5: out = [H|ctx] @ fc^T + b  (MFMA, N=128) ----------------
__global__ __launch_bounds__(256) void k_out2(const u16* __restrict__ Harc,
    const u16* __restrict__ Ctx, const u16* __restrict__ fc_bf,
    const float* __restrict__ fcb, float* __restrict__ out)
{
  __shared__ u16 As[128][40];
  __shared__ u16 Bs[128][40];
  const int tid = threadIdx.x;
  const int m0 = blockIdx.x * 128;
  const int l = tid & 63, w = tid >> 6;
  const int wr = w >> 1, wc = w & 1;
  const int lr = l & 15, lg = l >> 4;
  const int srow = tid >> 1, shalf = (tid & 1) * 16;
  f32x4 acc[4][4] = {};
  for (int k0 = 0; k0 < 2048; k0 += 32){
    {
      const u16* abase = (k0 < 1024) ? Harc : Ctx;
      const u16* a = abase + (size_t)(m0 + srow)*HD + (k0 & 1023) + shalf;
      ushort8 a0 = *(const ushort8*)a, a1 = *(const ushort8*)(a+8);
      const u16* b = fc_bf + (size_t)srow*2048 + k0 + shalf;
      ushort8 b0 = *(const ushort8*)b, b1 = *(const ushort8*)(b+8);
      *(ushort8*)&As[srow][shalf] = a0; *(ushort8*)&As[srow][shalf+8] = a1;
      *(ushort8*)&Bs[srow][shalf] = b0; *(ushort8*)&Bs[srow][shalf+8] = b1;
    }
    __syncthreads();
    bf16x8 af[4], bfr[4];
#pragma unroll
    for (int i = 0; i < 4; ++i){
      af[i]  = *(const bf16x8*)&As[wr*64 + i*16 + lr][lg*8];
      bfr[i] = *(const bf16x8*)&Bs[wc*64 + i*16 + lr][lg*8];
    }
#pragma unroll
    for (int i = 0; i < 4; ++i)
#pragma unroll
      for (int j = 0; j < 4; ++j)
        acc[i][j] = MFMA16(af[i], bfr[j], acc[i][j]);
    __syncthreads();
  }
#pragma unroll
  for (int i = 0; i < 4; ++i){
    const int row = m0 + wr*64 + i*16 + lg*4;
#pragma unroll
    for (int j = 0; j < 4; ++j){
      const int col = wc*64 + j*16 + lr;
      const float bias = fcb[col];
#pragma unroll
      for (int r = 0; r < 4; ++r)
        out[(size_t)(row + r)*NV + col] = acc[i][j][r] + bias;
    }
  }
}

extern "C" void kernel_launch(void* const* d_in, const int* in_sizes, int n_in,
                              void* d_out, int out_size, void* d_ws, size_t ws_size,
                              hipStream_t stream)
{
  const int*   x   = (const int*)  d_in[0];
  const float* emb = (const float*)d_in[1];
  const float* wxw = (const float*)d_in[2];
  const float* wxb = (const float*)d_in[3];
  const float* whw = (const float*)d_in[4];
  const float* whb = (const float*)d_in[5];
  const float* waw = (const float*)d_in[6];
  const float* wab = (const float*)d_in[7];
  const float* fcw = (const float*)d_in[8];
  const float* fcb = (const float*)d_in[9];
  float* out = (float*)d_out;

  char* ws = (char*)d_ws;
  unsigned int* cnt = (unsigned int*)(ws);            // 32 KB slot area (8 groups x 32 slots x 128B)
  float* hstate = (float*)(ws + 32768);               // 256 KB -> ends 294912
  float* XW     = (float*)(ws + 294912);              // 512 KB -> ends 819200
  u16*   Harc   = (u16*)  (ws + 819200);              // 64 MB  -> ends 67928064
  u16*   Aarc   = (u16*)  (ws + 67928064);            // 64 MB  -> ends 135036928 (reused as Ctx)
  u16*   SW     = (u16*)  (ws + 135036928);           // 64 MB  -> ends 202145792
  u16*   wa_bf  = (u16*)  (ws + 135036928);           // aliases SW (dead before scores)
  u16*   fc_bf  = (u16*)  (ws + 202145792);           // 512 KB -> total ~202.7 MB
  u16*   Ctx    = Aarc;                               // PV output overwrites A archive

  (void)hipMemsetAsync(ws, 0, 294912, stream);        // slots + hstate zeros

  k_cvt<<<dim3(5120), dim3(256), 0, stream>>>(waw, fcw, wa_bf, fc_bf);
  k_xw<<<dim3(NV), dim3(256), 0, stream>>>(emb, wxw, wxb, XW);

  {
    void* args[] = { (void*)&x, (void*)&whw, (void*)&whb, (void*)&XW,
                     (void*)&hstate, (void*)&Harc, (void*)&cnt };
    (void)hipLaunchCooperativeKernel((const void*)k_scan2, dim3(256), dim3(256),
                                     args, 0, stream);
  }

  k_gemm_A<<<dim3(256, 8), dim3(256), 0, stream>>>(Harc, wa_bf, wab, Aarc);
  k_scores<<<dim3(8, 8, 32), dim3(256), 0, stream>>>(Harc, Aarc, SW);
  k_softmax<<<dim3(32768), dim3(256), 0, stream>>>(SW);
  k_pv<<<dim3(8, 8, 32), dim3(256), 0, stream>>>(SW, Harc, Ctx);
  k_out2<<<dim3(256), dim3(256), 0, stream>>>(Harc, Ctx, fc_bf, fcb, out);
}

// Round 14
// 5029.725 us; speedup vs baseline: 1.1027x; 1.0103x over previous
//
#include <hip/hip_runtime.h>
#include <hip/hip_bf16.h>
#include <hip/hip_cooperative_groups.h>

#define NV 128
#define NE 256
#define HD 1024
#define NB 32
#define NS 1024

typedef unsigned short u16;
typedef unsigned long long u64;
typedef unsigned short ushort8 __attribute__((ext_vector_type(8)));
typedef unsigned short u16x4 __attribute__((ext_vector_type(4)));
typedef short bf16x8 __attribute__((ext_vector_type(8)));
typedef float f32x4 __attribute__((ext_vector_type(4)));

#define MFMA16(a, b, c) __builtin_amdgcn_mfma_f32_16x16x32_bf16(a, b, c, 0, 0, 0)

__device__ __forceinline__ float bf2f(u16 u){
  unsigned int x = ((unsigned int)u) << 16;
  return __builtin_bit_cast(float, x);
}
__device__ __forceinline__ u16 f2bf(float f){
  unsigned int u = __builtin_bit_cast(unsigned int, f);
  unsigned int r = u + 0x7fffu + ((u >> 16) & 1u);
  return (u16)(r >> 16);
}

// ---------------- K0: fp32 weights -> bf16 copies ----------------
__global__ __launch_bounds__(256) void k_cvt(const float* __restrict__ waw,
    const float* __restrict__ fcw, u16* __restrict__ wa_bf, u16* __restrict__ fc_bf)
{
  const int i = blockIdx.x * 256 + threadIdx.x;
  if (i < 1048576) wa_bf[i] = f2bf(waw[i]);
  const int j = i - 1048576;
  if (j >= 0 && j < 262144) fc_bf[j] = f2bf(fcw[j]);
}

// ---------------- K1: XW[v,h] = sum_e emb[v,e]*Wx[h,e] + Wx_b[h] ----------------
__global__ __launch_bounds__(256) void k_xw(const float* __restrict__ emb,
    const float* __restrict__ wxw, const float* __restrict__ wxb,
    float* __restrict__ XW)
{
  __shared__ float es[NE];
  const int v = blockIdx.x;
  for (int i = threadIdx.x; i < NE; i += 256) es[i] = emb[v*NE + i];
  __syncthreads();
  for (int h = threadIdx.x; h < HD; h += 256){
    const float* wr = wxw + (size_t)h * NE;
    float acc = 0.f;
#pragma unroll 4
    for (int e = 0; e < NE; e += 4){
      float4 w4 = *reinterpret_cast<const float4*>(wr + e);
      acc += w4.x*es[e] + w4.y*es[e+1] + w4.z*es[e+2] + w4.w*es[e+3];
    }
    XW[(size_t)v*HD + h] = acc + wxb[h];
  }
}

// ---------------- K2: RNN scan — TAGGED-DATA exchange, no barrier/flag/fence ----
// 256 WGs x 256 thr, 8 groups of 32 WGs; group g = bid&7 owns batches 4g..4g+3.
// h state lives as 8B atoms {tag:32 | fp32:32} in IC (write-through relaxed
// stores). Iteration t: consume tag==t (parity t&1), produce tag t+1 (parity
// (t+1)&1). Consumers gather their 16 coalesced pairs optimistically and
// re-poll only stale ones — the data is its own readiness flag, so the old
// drain->flag->poll->load chain (3 serialized IC RTs) collapses to ~1.
// Overwrite safety: tag t+1 is only overwritten (by t+3) after every group
// member consumed t+2, which requires t+1 fully consumed first.
__global__ __launch_bounds__(256, 1) void k_scan2(const int* __restrict__ x,
    const float* __restrict__ whw, const float* __restrict__ whb,
    const float* __restrict__ XW, u64* __restrict__ hstate,
    u16* __restrict__ Harc)
{
  __shared__ __align__(16) float hs[4096];   // 4 batches x 1024
  __shared__ int xs[4096];                   // 4 batches x 1024 token ids
  const int tid = threadIdx.x;
  const int g = blockIdx.x & 7;
  const int m = blockIdx.x >> 3;
  const int kc = tid & 31;
  const int rg = tid >> 5;
  const int row0 = m*32 + rg*4;

  for (int i = tid; i < 4096; i += 256) xs[i] = x[g*4096 + i];

  // Wh fragments: 4 rows x 32 k (8 float4), k-rotated to spread LDS banks
  float4 wv[4][8];
#pragma unroll
  for (int r = 0; r < 4; ++r)
#pragma unroll
    for (int j = 0; j < 8; ++j)
      wv[r][j] = *reinterpret_cast<const float4*>(
          whw + (size_t)(row0 + r)*HD + kc*32 + ((4*(j + kc)) & 31));

  // lane kc<16 of each rg writes (row rr, batch bb)
  const int rr = row0 + (kc & 3);
  const int bb = kc >> 2;
  const float bias = whb[rr];
  __syncthreads();                           // xs ready

  for (int t = 0; t < NS; ++t){
    const u64* hin  = hstate + (size_t)(t & 1)*(NB*HD) + g*4*HD;
    u64*       hout = hstate + (size_t)((t & 1)^1)*(NB*HD) + g*4*HD;
    const unsigned tg = (unsigned)t;
    // optimistic coalesced gather of this thread's 16 pairs
    u64 v[16];
#pragma unroll
    for (int q = 0; q < 16; ++q)
      v[q] = __hip_atomic_load(hin + q*256 + tid, __ATOMIC_RELAXED,
                               __HIP_MEMORY_SCOPE_AGENT);
    // re-poll only stale pairs until all carry tag t
    for (;;){
      bool ok = true;
#pragma unroll
      for (int q = 0; q < 16; ++q)
        if ((unsigned)(v[q] >> 32) != tg){
          ok = false;
          v[q] = __hip_atomic_load(hin + q*256 + tid, __ATOMIC_RELAXED,
                                   __HIP_MEMORY_SCOPE_AGENT);
        }
      if (ok) break;
      __builtin_amdgcn_s_sleep(1);
    }
#pragma unroll
    for (int q = 0; q < 16; ++q)
      hs[q*256 + tid] = __builtin_bit_cast(float, (unsigned)v[q]);
    // per-step gather operand (L1/L2-warm; no fence ever invalidates)
    float xwv = 0.f;
    if (kc < 16){
      const int xv = xs[bb*1024 + t];
      xwv = XW[(size_t)xv*HD + rr];
    }
    __syncthreads();

    float acc[4][4] = {};   // [row r][batch b]
#pragma unroll
    for (int j = 0; j < 8; ++j){
      const int off = kc*32 + ((4*(j + kc)) & 31);
      float4 h4[4];
#pragma unroll
      for (int b = 0; b < 4; ++b)
        h4[b] = *reinterpret_cast<const float4*>(&hs[b*1024 + off]);
#pragma unroll
      for (int r = 0; r < 4; ++r)
#pragma unroll
        for (int b = 0; b < 4; ++b)
          acc[r][b] += wv[r][j].x*h4[b].x + wv[r][j].y*h4[b].y
                     + wv[r][j].z*h4[b].z + wv[r][j].w*h4[b].w;
    }
    // butterfly reduce across the 32 kc-lanes (stays within each 32-lane half)
#pragma unroll
    for (int mm = 1; mm <= 16; mm <<= 1)
#pragma unroll
      for (int r = 0; r < 4; ++r)
#pragma unroll
        for (int b = 0; b < 4; ++b)
          acc[r][b] += __shfl_xor(acc[r][b], mm);
    // all lanes hold all 16 totals; lane kc<16 takes acc[kc&3][kc>>2]
    float sv = acc[0][0];
#pragma unroll
    for (int r = 0; r < 4; ++r)
#pragma unroll
      for (int b = 0; b < 4; ++b)
        if ((kc & 15) == b*4 + r) sv = acc[r][b];

    if (kc < 16){
      const float val = tanhf(xwv + bias + sv);
      const u64 pack = ((u64)(unsigned)(t + 1) << 32)
                     | (u64)__builtin_bit_cast(unsigned, val);
      // single WT store: the data carries its own readiness tag
      __hip_atomic_store(&hout[bb*HD + rr], pack, __ATOMIC_RELAXED,
                         __HIP_MEMORY_SCOPE_AGENT);
      Harc[(((size_t)(g*4 + bb))*NS + t)*HD + rr] = f2bf(val);
    }
    __syncthreads();   // protects hs reuse by next iteration's stage
  }
}

// ---------------- K3: A = H @ Wa^T + b  (MFMA, 128x128 tile) ----------------
__global__ __launch_bounds__(256) void k_gemm_A(const u16* __restrict__ Harc,
    const u16* __restrict__ wa_bf, const float* __restrict__ wab,
    u16* __restrict__ Aarc)
{
  __shared__ u16 As[128][40];
  __shared__ u16 Bs[128][40];
  const int tid = threadIdx.x;
  const int m0 = blockIdx.x * 128;
  const int n0 = blockIdx.y * 128;
  const int l = tid & 63, w = tid >> 6;
  const int wr = w >> 1, wc = w & 1;
  const int lr = l & 15, lg = l >> 4;
  const int srow = tid >> 1, shalf = (tid & 1) * 16;
  f32x4 acc[4][4] = {};
  for (int k0 = 0; k0 < 1024; k0 += 32){
    {
      const u16* a = Harc + (size_t)(m0 + srow)*HD + k0 + shalf;
      ushort8 a0 = *(const ushort8*)a, a1 = *(const ushort8*)(a+8);
      const u16* b = wa_bf + (size_t)(n0 + srow)*HD + k0 + shalf;
      ushort8 b0 = *(const ushort8*)b, b1 = *(const ushort8*)(b+8);
      *(ushort8*)&As[srow][shalf] = a0; *(ushort8*)&As[srow][shalf+8] = a1;
      *(ushort8*)&Bs[srow][shalf] = b0; *(ushort8*)&Bs[srow][shalf+8] = b1;
    }
    __syncthreads();
    bf16x8 af[4], bfr[4];
#pragma unroll
    for (int i = 0; i < 4; ++i){
      af[i]  = *(const bf16x8*)&As[wr*64 + i*16 + lr][lg*8];
      bfr[i] = *(const bf16x8*)&Bs[wc*64 + i*16 + lr][lg*8];
    }
#pragma unroll
    for (int i = 0; i < 4; ++i)
#pragma unroll
      for (int j = 0; j < 4; ++j)
        acc[i][j] = MFMA16(af[i], bfr[j], acc[i][j]);
    __syncthreads();
  }
#pragma unroll
  for (int i = 0; i < 4; ++i){
    const int row = m0 + wr*64 + i*16 + lg*4;
#pragma unroll
    for (int j = 0; j < 4; ++j){
      const int col = n0 + wc*64 + j*16 + lr;
      const float bias = wab[col];
#pragma unroll
      for (int r = 0; r < 4; ++r)
        Aarc[(size_t)(row + r)*HD + col] = f2bf(acc[i][j][r] + bias);
    }
  }
}

// ---------------- K4a: S[b,t,s] = H[b,t]·A[b,s]  (causal tiles only) ----------------
__global__ __launch_bounds__(256) void k_scores(const u16* __restrict__ Harc,
    const u16* __restrict__ Aarc, u16* __restrict__ SW)
{
  if (blockIdx.x > blockIdx.y) return;   // s-tile beyond t-tile: never read
  __shared__ u16 As[128][40];
  __shared__ u16 Bs[128][40];
  const int tid = threadIdx.x;
  const int bz = blockIdx.z;
  const int m0 = blockIdx.y * 128;   // t
  const int n0 = blockIdx.x * 128;   // s
  const u16* Hb = Harc + (size_t)bz * NS * HD;
  const u16* Ab = Aarc + (size_t)bz * NS * HD;
  u16* Sb = SW + ((size_t)bz << 20);
  const int l = tid & 63, w = tid >> 6;
  const int wr = w >> 1, wc = w & 1;
  const int lr = l & 15, lg = l >> 4;
  const int srow = tid >> 1, shalf = (tid & 1) * 16;
  f32x4 acc[4][4] = {};
  for (int k0 = 0; k0 < 1024; k0 += 32){
    {
      const u16* a = Hb + (size_t)(m0 + srow)*HD + k0 + shalf;
      ushort8 a0 = *(const ushort8*)a, a1 = *(const ushort8*)(a+8);
      const u16* b = Ab + (size_t)(n0 + srow)*HD + k0 + shalf;
      ushort8 b0 = *(const ushort8*)b, b1 = *(const ushort8*)(b+8);
      *(ushort8*)&As[srow][shalf] = a0; *(ushort8*)&As[srow][shalf+8] = a1;
      *(ushort8*)&Bs[srow][shalf] = b0; *(ushort8*)&Bs[srow][shalf+8] = b1;
    }
    __syncthreads();
    bf16x8 af[4], bfr[4];
#pragma unroll
    for (int i = 0; i < 4; ++i){
      af[i]  = *(const bf16x8*)&As[wr*64 + i*16 + lr][lg*8];
      bfr[i] = *(const bf16x8*)&Bs[wc*64 + i*16 + lr][lg*8];
    }
#pragma unroll
    for (int i = 0; i < 4; ++i)
#pragma unroll
      for (int j = 0; j < 4; ++j)
        acc[i][j] = MFMA16(af[i], bfr[j], acc[i][j]);
    __syncthreads();
  }
#pragma unroll
  for (int i = 0; i < 4; ++i){
    const int row = m0 + wr*64 + i*16 + lg*4;
#pragma unroll
    for (int j = 0; j < 4; ++j){
      const int col = n0 + wc*64 + j*16 + lr;
#pragma unroll
      for (int r = 0; r < 4; ++r)
        Sb[((size_t)(row + r) << 10) + col] = f2bf(acc[i][j][r]);
    }
  }
}

// ---------------- K4b: row softmax over s (in place, zero-fill s>t) ----------------
__global__ __launch_bounds__(256) void k_softmax(u16* __restrict__ SW)
{
  const int bid = blockIdx.x;
  const int b = bid >> 10, t = bid & 1023;
  u16* row = SW + ((size_t)b << 20) + ((size_t)t << 10);
  const int i0 = threadIdx.x * 4;
  u16x4 v = *(const u16x4*)(row + i0);
  float x[4];
#pragma unroll
  for (int j = 0; j < 4; ++j) x[j] = (i0 + j <= t) ? bf2f(v[j]) : -1e30f;
  float m = fmaxf(fmaxf(x[0], x[1]), fmaxf(x[2], x[3]));
#pragma unroll
  for (int o = 1; o < 64; o <<= 1) m = fmaxf(m, __shfl_xor(m, o));
  __shared__ float redm[4], reds[4];
  if ((threadIdx.x & 63) == 0) redm[threadIdx.x >> 6] = m;
  __syncthreads();
  m = fmaxf(fmaxf(redm[0], redm[1]), fmaxf(redm[2], redm[3]));
  float e[4]; float s = 0.f;
#pragma unroll
  for (int j = 0; j < 4; ++j){ e[j] = __expf(x[j] - m); s += e[j]; }
#pragma unroll
  for (int o = 1; o < 64; o <<= 1) s += __shfl_xor(s, o);
  if ((threadIdx.x & 63) == 0) reds[threadIdx.x >> 6] = s;
  __syncthreads();
  s = reds[0] + reds[1] + reds[2] + reds[3];
  const float inv = 1.f / s;
  u16x4 o4;
#pragma unroll
  for (int j = 0; j < 4; ++j) o4[j] = f2bf(e[j] * inv);
  *(u16x4*)(row + i0) = o4;
}

// ---------------- K4c: Ctx[b,t,e] = sum_s W[b,t,s] * H[b,s,e] ----------------
__global__ __launch_bounds__(256) void k_pv(const u16* __restrict__ SW,
    const u16* __restrict__ Harc, u16* __restrict__ Ctx)
{
  __shared__ u16 As[128][40];   // W rows t, cols s
  __shared__ u16 Bs[128][40];   // H^T rows e, cols s
  const int tid = threadIdx.x;
  const int bz = blockIdx.z;
  const int t0 = blockIdx.x * 128;
  const int e0 = blockIdx.y * 128;
  const u16* Wb = SW + ((size_t)bz << 20);
  const u16* Hb = Harc + (size_t)bz * NS * HD;
  u16* Cb = Ctx + (size_t)bz * NS * HD;
  const int l = tid & 63, w = tid >> 6;
  const int wr = w >> 1, wc = w & 1;
  const int lr = l & 15, lg = l >> 4;
  const int srow = tid >> 1, shalf = (tid & 1) * 16;
  const int sIdx = tid & 31, ec = tid >> 5;
  const int ksteps = (blockIdx.x + 1) * 4;    // s < t0 + 128 (causal bound)
  f32x4 acc[4][4] = {};
  for (int ks = 0; ks < ksteps; ++ks){
    const int k0 = ks * 32;
    {
      const u16* a = Wb + ((size_t)(t0 + srow) << 10) + k0 + shalf;
      ushort8 a0 = *(const ushort8*)a, a1 = *(const ushort8*)(a+8);
      const u16* b = Hb + (size_t)(k0 + sIdx)*HD + e0 + ec*16;
      ushort8 b0 = *(const ushort8*)b, b1 = *(const ushort8*)(b+8);
      *(ushort8*)&As[srow][shalf] = a0; *(ushort8*)&As[srow][shalf+8] = a1;
#pragma unroll
      for (int i = 0; i < 8; ++i){
        Bs[ec*16 + i][sIdx] = b0[i];
        Bs[ec*16 + 8 + i][sIdx] = b1[i];
      }
    }
    __syncthreads();
    bf16x8 af[4], bfr[4];
#pragma unroll
    for (int i = 0; i < 4; ++i){
      af[i]  = *(const bf16x8*)&As[wr*64 + i*16 + lr][lg*8];
      bfr[i] = *(const bf16x8*)&Bs[wc*64 + i*16 + lr][lg*8];
    }
#pragma unroll
    for (int i = 0; i < 4; ++i)
#pragma unroll
      for (int j = 0; j < 4; ++j)
        acc[i][j] = MFMA16(af[i], bfr[j], acc[i][j]);
    __syncthreads();
  }
#pragma unroll
  for (int i = 0; i < 4; ++i){
    const int row = t0 + wr*64 + i*16 + lg*4;
#pragma unroll
    for (int j = 0; j < 4; ++j){
      const int col = e0 + wc*64 + j*16 + lr;
#pragma unroll
      for (int r = 0; r < 4; ++r)
        Cb[(size_t)(row + r)*HD + col] = f2bf(acc[i][j][r]);
    }
  }
}

// ---------------- K5: out = [H|ctx] @ fc^T + b  (MFMA, N=128) ----------------
__global__ __launch_bounds__(256) void k_out2(const u16* __restrict__ Harc,
    const u16* __restrict__ Ctx, const u16* __restrict__ fc_bf,
    const float* __restrict__ fcb, float* __restrict__ out)
{
  __shared__ u16 As[128][40];
  __shared__ u16 Bs[128][40];
  const int tid = threadIdx.x;
  const int m0 = blockIdx.x * 128;
  const int l = tid & 63, w = tid >> 6;
  const int wr = w >> 1, wc = w & 1;
  const int lr = l & 15, lg = l >> 4;
  const int srow = tid >> 1, shalf = (tid & 1) * 16;
  f32x4 acc[4][4] = {};
  for (int k0 = 0; k0 < 2048; k0 += 32){
    {
      const u16* abase = (k0 < 1024) ? Harc : Ctx;
      const u16* a = abase + (size_t)(m0 + srow)*HD + (k0 & 1023) + shalf;
      ushort8 a0 = *(const ushort8*)a, a1 = *(const ushort8*)(a+8);
      const u16* b = fc_bf + (size_t)srow*2048 + k0 + shalf;
      ushort8 b0 = *(const ushort8*)b, b1 = *(const ushort8*)(b+8);
      *(ushort8*)&As[srow][shalf] = a0; *(ushort8*)&As[srow][shalf+8] = a1;
      *(ushort8*)&Bs[srow][shalf] = b0; *(ushort8*)&Bs[srow][shalf+8] = b1;
    }
    __syncthreads();
    bf16x8 af[4], bfr[4];
#pragma unroll
    for (int i = 0; i < 4; ++i){
      af[i]  = *(const bf16x8*)&As[wr*64 + i*16 + lr][lg*8];
      bfr[i] = *(const bf16x8*)&Bs[wc*64 + i*16 + lr][lg*8];
    }
#pragma unroll
    for (int i = 0; i < 4; ++i)
#pragma unroll
      for (int j = 0; j < 4; ++j)
        acc[i][j] = MFMA16(af[i], bfr[j], acc[i][j]);
    __syncthreads();
  }
#pragma unroll
  for (int i = 0; i < 4; ++i){
    const int row = m0 + wr*64 + i*16 + lg*4;
#pragma unroll
    for (int j = 0; j < 4; ++j){
      const int col = wc*64 + j*16 + lr;
      const float bias = fcb[col];
#pragma unroll
      for (int r = 0; r < 4; ++r)
        out[(size_t)(row + r)*NV + col] = acc[i][j][r] + bias;
    }
  }
}

extern "C" void kernel_launch(void* const* d_in, const int* in_sizes, int n_in,
                              void* d_out, int out_size, void* d_ws, size_t ws_size,
                              hipStream_t stream)
{
  const int*   x   = (const int*)  d_in[0];
  const float* emb = (const float*)d_in[1];
  const float* wxw = (const float*)d_in[2];
  const float* wxb = (const float*)d_in[3];
  const float* whw = (const float*)d_in[4];
  const float* whb = (const float*)d_in[5];
  const float* waw = (const float*)d_in[6];
  const float* wab = (const float*)d_in[7];
  const float* fcw = (const float*)d_in[8];
  const float* fcb = (const float*)d_in[9];
  float* out = (float*)d_out;

  char* ws = (char*)d_ws;
  u64*   hstate = (u64*)  (ws);                       // 512 KB: 2 parities x 32x1024 pairs
  float* XW     = (float*)(ws + 524288);              // 512 KB -> ends 1048576
  u16*   Harc   = (u16*)  (ws + 1048576);             // 64 MB  -> ends 68157440
  u16*   Aarc   = (u16*)  (ws + 68157440);            // 64 MB  -> ends 135266304 (reused as Ctx)
  u16*   SW     = (u16*)  (ws + 135266304);           // 64 MB  -> ends 202375168
  u16*   wa_bf  = (u16*)  (ws + 135266304);           // aliases SW (dead before scores)
  u16*   fc_bf  = (u16*)  (ws + 202375168);           // 512 KB -> total ~202.9 MB
  u16*   Ctx    = Aarc;                               // PV output overwrites A archive

  (void)hipMemsetAsync(ws, 0, 524288, stream);        // hstate zeros = {tag 0, 0.0f}

  k_cvt<<<dim3(5120), dim3(256), 0, stream>>>(waw, fcw, wa_bf, fc_bf);
  k_xw<<<dim3(NV), dim3(256), 0, stream>>>(emb, wxw, wxb, XW);

  {
    void* args[] = { (void*)&x, (void*)&whw, (void*)&whb, (void*)&XW,
                     (void*)&hstate, (void*)&Harc };
    (void)hipLaunchCooperativeKernel((const void*)k_scan2, dim3(256), dim3(256),
                                     args, 0, stream);
  }

  k_gemm_A<<<dim3(256, 8), dim3(256), 0, stream>>>(Harc, wa_bf, wab, Aarc);
  k_scores<<<dim3(8, 8, 32), dim3(256), 0, stream>>>(Harc, Aarc, SW);
  k_softmax<<<dim3(32768), dim3(256), 0, stream>>>(SW);
  k_pv<<<dim3(8, 8, 32), dim3(256), 0, stream>>>(SW, Harc, Ctx);
  k_out2<<<dim3(256), dim3(256), 0, stream>>>(Harc, Ctx, fc_bf, fcb, out);
}

// Round 15
// 4968.620 us; speedup vs baseline: 1.1163x; 1.0123x over previous
//
#include <hip/hip_runtime.h>
#include <hip/hip_bf16.h>
#include <hip/hip_cooperative_groups.h>

#define NV 128
#define NE 256
#define HD 1024
#define NB 32
#define NS 1024

typedef unsigned short u16;
typedef unsigned long long u64;
typedef unsigned short ushort8 __attribute__((ext_vector_type(8)));
typedef unsigned short u16x4 __attribute__((ext_vector_type(4)));
typedef short bf16x8 __attribute__((ext_vector_type(8)));
typedef float f32x4 __attribute__((ext_vector_type(4)));

#define MFMA16(a, b, c) __builtin_amdgcn_mfma_f32_16x16x32_bf16(a, b, c, 0, 0, 0)

__device__ __forceinline__ float bf2f(u16 u){
  unsigned int x = ((unsigned int)u) << 16;
  return __builtin_bit_cast(float, x);
}
__device__ __forceinline__ u16 f2bf(float f){
  unsigned int u = __builtin_bit_cast(unsigned int, f);
  unsigned int r = u + 0x7fffu + ((u >> 16) & 1u);
  return (u16)(r >> 16);
}

// ---------------- K0: fp32 weights -> bf16 copies ----------------
__global__ __launch_bounds__(256) void k_cvt(const float* __restrict__ waw,
    const float* __restrict__ fcw, u16* __restrict__ wa_bf, u16* __restrict__ fc_bf)
{
  const int i = blockIdx.x * 256 + threadIdx.x;
  if (i < 1048576) wa_bf[i] = f2bf(waw[i]);
  const int j = i - 1048576;
  if (j >= 0 && j < 262144) fc_bf[j] = f2bf(fcw[j]);
}

// ---------------- K1: XW[v,h] = sum_e emb[v,e]*Wx[h,e] + Wx_b[h] ----------------
__global__ __launch_bounds__(256) void k_xw(const float* __restrict__ emb,
    const float* __restrict__ wxw, const float* __restrict__ wxb,
    float* __restrict__ XW)
{
  __shared__ float es[NE];
  const int v = blockIdx.x;
  for (int i = threadIdx.x; i < NE; i += 256) es[i] = emb[v*NE + i];
  __syncthreads();
  for (int h = threadIdx.x; h < HD; h += 256){
    const float* wr = wxw + (size_t)h * NE;
    float acc = 0.f;
#pragma unroll 4
    for (int e = 0; e < NE; e += 4){
      float4 w4 = *reinterpret_cast<const float4*>(wr + e);
      acc += w4.x*es[e] + w4.y*es[e+1] + w4.z*es[e+2] + w4.w*es[e+3];
    }
    XW[(size_t)v*HD + h] = acc + wxb[h];
  }
}

// ---------------- K2: RNN scan — 2-phase tagged pipeline, full 256-WG grid -----
// 256 WGs x 256 thr, 8 groups of 32 WGs; group g = bid&7 owns batches 4g..4g+3,
// split into phase A = {4g,4g+1} and phase B = {4g+2,4g+3}. Tagged-data
// exchange (R14): h pairs {tag:32|fp32:32}, WT relaxed agent stores, no
// barrier/flag/fence. While a WG computes+stores phase A, phase B's stores
// (from the previous iteration) age toward IC visibility — the visibility
// latency V (~2.6us) is paid half-exposed per phase instead of fully per step:
// period ~ 2*((V-0.65)/2 + 0.65) instead of V + 1.3.
__global__ __launch_bounds__(256, 2) void k_scan2(const int* __restrict__ x,
    const float* __restrict__ whw, const float* __restrict__ whb,
    const float* __restrict__ XW, u64* __restrict__ hstate,
    u16* __restrict__ Harc)
{
  __shared__ __align__(16) float hsA[2048];  // 2 batches x 1024
  __shared__ __align__(16) float hsB[2048];  // 2 batches x 1024
  __shared__ int xs[4096];                   // 4 batches x 1024 token ids
  const int tid = threadIdx.x;
  const int g = blockIdx.x & 7;
  const int m = blockIdx.x >> 3;
  const int kc = tid & 31;
  const int rg = tid >> 5;
  const int row0 = m*32 + rg*4;

  for (int i = tid; i < 4096; i += 256) xs[i] = x[g*4096 + i];

  // Wh fragments: 4 rows x 32 k (8 float4), k-rotated to spread LDS banks
  float4 wv[4][8];
#pragma unroll
  for (int r = 0; r < 4; ++r)
#pragma unroll
    for (int j = 0; j < 8; ++j)
      wv[r][j] = *reinterpret_cast<const float4*>(
          whw + (size_t)(row0 + r)*HD + kc*32 + ((4*(j + kc)) & 31));

  // writer lanes: kc<8 of each rg handle (row rr, batch-within-phase bbp)
  const int rr = row0 + (kc & 3);
  const int bbp = (kc >> 2) & 1;
  const float bias = whb[rr];
  __syncthreads();                           // xs ready

  for (int t = 0; t < NS; ++t){
    const unsigned tg = (unsigned)t;
    const u64* hinA  = hstate + (size_t)(t & 1)*(NB*HD) + g*4096;
    u64*       houtA = hstate + (size_t)((t & 1)^1)*(NB*HD) + g*4096;
    const u64* hinB  = hinA + 2048;
    u64*       houtB = houtA + 2048;

    // ================= phase A (batches 4g, 4g+1) =================
    {
      u64 v[8];
#pragma unroll
      for (int q = 0; q < 8; ++q)
        v[q] = __hip_atomic_load(hinA + q*256 + tid, __ATOMIC_RELAXED,
                                 __HIP_MEMORY_SCOPE_AGENT);
      for (;;){
        bool ok = true;
#pragma unroll
        for (int q = 0; q < 8; ++q)
          if ((unsigned)(v[q] >> 32) != tg){
            ok = false;
            v[q] = __hip_atomic_load(hinA + q*256 + tid, __ATOMIC_RELAXED,
                                     __HIP_MEMORY_SCOPE_AGENT);
          }
        if (ok) break;
        __builtin_amdgcn_s_sleep(1);
      }
#pragma unroll
      for (int q = 0; q < 8; ++q)
        hsA[q*256 + tid] = __builtin_bit_cast(float, (unsigned)v[q]);
      float xwv = 0.f;
      if (kc < 8) xwv = XW[(size_t)xs[bbp*1024 + t]*HD + rr];
      __syncthreads();   // hsA ready

      float acc[4][2] = {};
#pragma unroll
      for (int j = 0; j < 8; ++j){
        const int off = kc*32 + ((4*(j + kc)) & 31);
        float4 h0 = *reinterpret_cast<const float4*>(&hsA[off]);
        float4 h1 = *reinterpret_cast<const float4*>(&hsA[1024 + off]);
#pragma unroll
        for (int r = 0; r < 4; ++r){
          acc[r][0] += wv[r][j].x*h0.x + wv[r][j].y*h0.y
                     + wv[r][j].z*h0.z + wv[r][j].w*h0.w;
          acc[r][1] += wv[r][j].x*h1.x + wv[r][j].y*h1.y
                     + wv[r][j].z*h1.z + wv[r][j].w*h1.w;
        }
      }
#pragma unroll
      for (int mm = 1; mm <= 16; mm <<= 1)
#pragma unroll
        for (int r = 0; r < 4; ++r){
          acc[r][0] += __shfl_xor(acc[r][0], mm);
          acc[r][1] += __shfl_xor(acc[r][1], mm);
        }
      float sv = acc[0][0];
#pragma unroll
      for (int r = 0; r < 4; ++r)
#pragma unroll
        for (int b = 0; b < 2; ++b)
          if ((kc & 7) == b*4 + r) sv = acc[r][b];
      if (kc < 8){
        const float val = tanhf(xwv + bias + sv);
        const u64 pack = ((u64)(unsigned)(t + 1) << 32)
                       | (u64)__builtin_bit_cast(unsigned, val);
        __hip_atomic_store(&houtA[bbp*1024 + rr], pack, __ATOMIC_RELAXED,
                           __HIP_MEMORY_SCOPE_AGENT);
        Harc[(((size_t)(g*4 + bbp))*NS + t)*HD + rr] = f2bf(val);
      }
    }

    // ================= phase B (batches 4g+2, 4g+3) =================
    {
      u64 v[8];
#pragma unroll
      for (int q = 0; q < 8; ++q)
        v[q] = __hip_atomic_load(hinB + q*256 + tid, __ATOMIC_RELAXED,
                                 __HIP_MEMORY_SCOPE_AGENT);
      for (;;){
        bool ok = true;
#pragma unroll
        for (int q = 0; q < 8; ++q)
          if ((unsigned)(v[q] >> 32) != tg){
            ok = false;
            v[q] = __hip_atomic_load(hinB + q*256 + tid, __ATOMIC_RELAXED,
                                     __HIP_MEMORY_SCOPE_AGENT);
          }
        if (ok) break;
        __builtin_amdgcn_s_sleep(1);
      }
#pragma unroll
      for (int q = 0; q < 8; ++q)
        hsB[q*256 + tid] = __builtin_bit_cast(float, (unsigned)v[q]);
      float xwv = 0.f;
      if (kc < 8) xwv = XW[(size_t)xs[(2 + bbp)*1024 + t]*HD + rr];
      __syncthreads();   // hsB ready

      float acc[4][2] = {};
#pragma unroll
      for (int j = 0; j < 8; ++j){
        const int off = kc*32 + ((4*(j + kc)) & 31);
        float4 h0 = *reinterpret_cast<const float4*>(&hsB[off]);
        float4 h1 = *reinterpret_cast<const float4*>(&hsB[1024 + off]);
#pragma unroll
        for (int r = 0; r < 4; ++r){
          acc[r][0] += wv[r][j].x*h0.x + wv[r][j].y*h0.y
                     + wv[r][j].z*h0.z + wv[r][j].w*h0.w;
          acc[r][1] += wv[r][j].x*h1.x + wv[r][j].y*h1.y
                     + wv[r][j].z*h1.z + wv[r][j].w*h1.w;
        }
      }
#pragma unroll
      for (int mm = 1; mm <= 16; mm <<= 1)
#pragma unroll
        for (int r = 0; r < 4; ++r){
          acc[r][0] += __shfl_xor(acc[r][0], mm);
          acc[r][1] += __shfl_xor(acc[r][1], mm);
        }
      float sv = acc[0][0];
#pragma unroll
      for (int r = 0; r < 4; ++r)
#pragma unroll
        for (int b = 0; b < 2; ++b)
          if ((kc & 7) == b*4 + r) sv = acc[r][b];
      if (kc < 8){
        const float val = tanhf(xwv + bias + sv);
        const u64 pack = ((u64)(unsigned)(t + 1) << 32)
                       | (u64)__builtin_bit_cast(unsigned, val);
        __hip_atomic_store(&houtB[bbp*1024 + rr], pack, __ATOMIC_RELAXED,
                           __HIP_MEMORY_SCOPE_AGENT);
        Harc[(((size_t)(g*4 + 2 + bbp))*NS + t)*HD + rr] = f2bf(val);
      }
    }
    __syncthreads();   // protect hsA/hsB reuse by next iteration's staging
  }
}

// ---------------- K3: A = H @ Wa^T + b  (MFMA, 128x128 tile) ----------------
__global__ __launch_bounds__(256) void k_gemm_A(const u16* __restrict__ Harc,
    const u16* __restrict__ wa_bf, const float* __restrict__ wab,
    u16* __restrict__ Aarc)
{
  __shared__ u16 As[128][40];
  __shared__ u16 Bs[128][40];
  const int tid = threadIdx.x;
  const int m0 = blockIdx.x * 128;
  const int n0 = blockIdx.y * 128;
  const int l = tid & 63, w = tid >> 6;
  const int wr = w >> 1, wc = w & 1;
  const int lr = l & 15, lg = l >> 4;
  const int srow = tid >> 1, shalf = (tid & 1) * 16;
  f32x4 acc[4][4] = {};
  for (int k0 = 0; k0 < 1024; k0 += 32){
    {
      const u16* a = Harc + (size_t)(m0 + srow)*HD + k0 + shalf;
      ushort8 a0 = *(const ushort8*)a, a1 = *(const ushort8*)(a+8);
      const u16* b = wa_bf + (size_t)(n0 + srow)*HD + k0 + shalf;
      ushort8 b0 = *(const ushort8*)b, b1 = *(const ushort8*)(b+8);
      *(ushort8*)&As[srow][shalf] = a0; *(ushort8*)&As[srow][shalf+8] = a1;
      *(ushort8*)&Bs[srow][shalf] = b0; *(ushort8*)&Bs[srow][shalf+8] = b1;
    }
    __syncthreads();
    bf16x8 af[4], bfr[4];
#pragma unroll
    for (int i = 0; i < 4; ++i){
      af[i]  = *(const bf16x8*)&As[wr*64 + i*16 + lr][lg*8];
      bfr[i] = *(const bf16x8*)&Bs[wc*64 + i*16 + lr][lg*8];
    }
#pragma unroll
    for (int i = 0; i < 4; ++i)
#pragma unroll
      for (int j = 0; j < 4; ++j)
        acc[i][j] = MFMA16(af[i], bfr[j], acc[i][j]);
    __syncthreads();
  }
#pragma unroll
  for (int i = 0; i < 4; ++i){
    const int row = m0 + wr*64 + i*16 + lg*4;
#pragma unroll
    for (int j = 0; j < 4; ++j){
      const int col = n0 + wc*64 + j*16 + lr;
      const float bias = wab[col];
#pragma unroll
      for (int r = 0; r < 4; ++r)
        Aarc[(size_t)(row + r)*HD + col] = f2bf(acc[i][j][r] + bias);
    }
  }
}

// ---------------- K4a: S[b,t,s] = H[b,t]·A[b,s]  (causal tiles only) ----------------
__global__ __launch_bounds__(256) void k_scores(const u16* __restrict__ Harc,
    const u16* __restrict__ Aarc, u16* __restrict__ SW)
{
  if (blockIdx.x > blockIdx.y) return;   // s-tile beyond t-tile: never read
  __shared__ u16 As[128][40];
  __shared__ u16 Bs[128][40];
  const int tid = threadIdx.x;
  const int bz = blockIdx.z;
  const int m0 = blockIdx.y * 128;   // t
  const int n0 = blockIdx.x * 128;   // s
  const u16* Hb = Harc + (size_t)bz * NS * HD;
  const u16* Ab = Aarc + (size_t)bz * NS * HD;
  u16* Sb = SW + ((size_t)bz << 20);
  const int l = tid & 63, w = tid >> 6;
  const int wr = w >> 1, wc = w & 1;
  const int lr = l & 15, lg = l >> 4;
  const int srow = tid >> 1, shalf = (tid & 1) * 16;
  f32x4 acc[4][4] = {};
  for (int k0 = 0; k0 < 1024; k0 += 32){
    {
      const u16* a = Hb + (size_t)(m0 + srow)*HD + k0 + shalf;
      ushort8 a0 = *(const ushort8*)a, a1 = *(const ushort8*)(a+8);
      const u16* b = Ab + (size_t)(n0 + srow)*HD + k0 + shalf;
      ushort8 b0 = *(const ushort8*)b, b1 = *(const ushort8*)(b+8);
      *(ushort8*)&As[srow][shalf] = a0; *(ushort8*)&As[srow][shalf+8] = a1;
      *(ushort8*)&Bs[srow][shalf] = b0; *(ushort8*)&Bs[srow][shalf+8] = b1;
    }
    __syncthreads();
    bf16x8 af[4], bfr[4];
#pragma unroll
    for (int i = 0; i < 4; ++i){
      af[i]  = *(const bf16x8*)&As[wr*64 + i*16 + lr][lg*8];
      bfr[i] = *(const bf16x8*)&Bs[wc*64 + i*16 + lr][lg*8];
    }
#pragma unroll
    for (int i = 0; i < 4; ++i)
#pragma unroll
      for (int j = 0; j < 4; ++j)
        acc[i][j] = MFMA16(af[i], bfr[j], acc[i][j]);
    __syncthreads();
  }
#pragma unroll
  for (int i = 0; i < 4; ++i){
    const int row = m0 + wr*64 + i*16 + lg*4;
#pragma unroll
    for (int j = 0; j < 4; ++j){
      const int col = n0 + wc*64 + j*16 + lr;
#pragma unroll
      for (int r = 0; r < 4; ++r)
        Sb[((size_t)(row + r) << 10) + col] = f2bf(acc[i][j][r]);
    }
  }
}

// ---------------- K4b: row softmax over s (in place, zero-fill s>t) ----------------
__global__ __launch_bounds__(256) void k_softmax(u16* __restrict__ SW)
{
  const int bid = blockIdx.x;
  const int b = bid >> 10, t = bid & 1023;
  u16* row = SW + ((size_t)b << 20) + ((size_t)t << 10);
  const int i0 = threadIdx.x * 4;
  u16x4 v = *(const u16x4*)(row + i0);
  float x[4];
#pragma unroll
  for (int j = 0; j < 4; ++j) x[j] = (i0 + j <= t) ? bf2f(v[j]) : -1e30f;
  float m = fmaxf(fmaxf(x[0], x[1]), fmaxf(x[2], x[3]));
#pragma unroll
  for (int o = 1; o < 64; o <<= 1) m = fmaxf(m, __shfl_xor(m, o));
  __shared__ float redm[4], reds[4];
  if ((threadIdx.x & 63) == 0) redm[threadIdx.x >> 6] = m;
  __syncthreads();
  m = fmaxf(fmaxf(redm[0], redm[1]), fmaxf(redm[2], redm[3]));
  float e[4]; float s = 0.f;
#pragma unroll
  for (int j = 0; j < 4; ++j){ e[j] = __expf(x[j] - m); s += e[j]; }
#pragma unroll
  for (int o = 1; o < 64; o <<= 1) s += __shfl_xor(s, o);
  if ((threadIdx.x & 63) == 0) reds[threadIdx.x >> 6] = s;
  __syncthreads();
  s = reds[0] + reds[1] + reds[2] + reds[3];
  const float inv = 1.f / s;
  u16x4 o4;
#pragma unroll
  for (int j = 0; j < 4; ++j) o4[j] = f2bf(e[j] * inv);
  *(u16x4*)(row + i0) = o4;
}

// ---------------- K4c: Ctx[b,t,e] = sum_s W[b,t,s] * H[b,s,e] ----------------
__global__ __launch_bounds__(256) void k_pv(const u16* __restrict__ SW,
    const u16* __restrict__ Harc, u16* __restrict__ Ctx)
{
  __shared__ u16 As[128][40];   // W rows t, cols s
  __shared__ u16 Bs[128][40];   // H^T rows e, cols s
  const int tid = threadIdx.x;
  const int bz = blockIdx.z;
  const int t0 = blockIdx.x * 128;
  const int e0 = blockIdx.y * 128;
  const u16* Wb = SW + ((size_t)bz << 20);
  const u16* Hb = Harc + (size_t)bz * NS * HD;
  u16* Cb = Ctx + (size_t)bz * NS * HD;
  const int l = tid & 63, w = tid >> 6;
  const int wr = w >> 1, wc = w & 1;
  const int lr = l & 15, lg = l >> 4;
  const int srow = tid >> 1, shalf = (tid & 1) * 16;
  const int sIdx = tid & 31, ec = tid >> 5;
  const int ksteps = (blockIdx.x + 1) * 4;    // s < t0 + 128 (causal bound)
  f32x4 acc[4][4] = {};
  for (int ks = 0; ks < ksteps; ++ks){
    const int k0 = ks * 32;
    {
      const u16* a = Wb + ((size_t)(t0 + srow) << 10) + k0 + shalf;
      ushort8 a0 = *(const ushort8*)a, a1 = *(const ushort8*)(a+8);
      const u16* b = Hb + (size_t)(k0 + sIdx)*HD + e0 + ec*16;
      ushort8 b0 = *(const ushort8*)b, b1 = *(const ushort8*)(b+8);
      *(ushort8*)&As[srow][shalf] = a0; *(ushort8*)&As[srow][shalf+8] = a1;
#pragma unroll
      for (int i = 0; i < 8; ++i){
        Bs[ec*16 + i][sIdx] = b0[i];
        Bs[ec*16 + 8 + i][sIdx] = b1[i];
      }
    }
    __syncthreads();
    bf16x8 af[4], bfr[4];
#pragma unroll
    for (int i = 0; i < 4; ++i){
      af[i]  = *(const bf16x8*)&As[wr*64 + i*16 + lr][lg*8];
      bfr[i] = *(const bf16x8*)&Bs[wc*64 + i*16 + lr][lg*8];
    }
#pragma unroll
    for (int i = 0; i < 4; ++i)
#pragma unroll
      for (int j = 0; j < 4; ++j)
        acc[i][j] = MFMA16(af[i], bfr[j], acc[i][j]);
    __syncthreads();
  }
#pragma unroll
  for (int i = 0; i < 4; ++i){
    const int row = t0 + wr*64 + i*16 + lg*4;
#pragma unroll
    for (int j = 0; j < 4; ++j){
      const int col = e0 + wc*64 + j*16 + lr;
#pragma unroll
      for (int r = 0; r < 4; ++r)
        Cb[(size_t)(row + r)*HD + col] = f2bf(acc[i][j][r]);
    }
  }
}

// ---------------- K5: out = [H|ctx] @ fc^T + b  (MFMA, N=128) ----------------
__global__ __launch_bounds__(256) void k_out2(const u16* __restrict__ Harc,
    const u16* __restrict__ Ctx, const u16* __restrict__ fc_bf,
    const float* __restrict__ fcb, float* __restrict__ out)
{
  __shared__ u16 As[128][40];
  __shared__ u16 Bs[128][40];
  const int tid = threadIdx.x;
  const int m0 = blockIdx.x * 128;
  const int l = tid & 63, w = tid >> 6;
  const int wr = w >> 1, wc = w & 1;
  const int lr = l & 15, lg = l >> 4;
  const int srow = tid >> 1, shalf = (tid & 1) * 16;
  f32x4 acc[4][4] = {};
  for (int k0 = 0; k0 < 2048; k0 += 32){
    {
      const u16* abase = (k0 < 1024) ? Harc : Ctx;
      const u16* a = abase + (size_t)(m0 + srow)*HD + (k0 & 1023) + shalf;
      ushort8 a0 = *(const ushort8*)a, a1 = *(const ushort8*)(a+8);
      const u16* b = fc_bf + (size_t)srow*2048 + k0 + shalf;
      ushort8 b0 = *(const ushort8*)b, b1 = *(const ushort8*)(b+8);
      *(ushort8*)&As[srow][shalf] = a0; *(ushort8*)&As[srow][shalf+8] = a1;
      *(ushort8*)&Bs[srow][shalf] = b0; *(ushort8*)&Bs[srow][shalf+8] = b1;
    }
    __syncthreads();
    bf16x8 af[4], bfr[4];
#pragma unroll
    for (int i = 0; i < 4; ++i){
      af[i]  = *(const bf16x8*)&As[wr*64 + i*16 + lr][lg*8];
      bfr[i] = *(const bf16x8*)&Bs[wc*64 + i*16 + lr][lg*8];
    }
#pragma unroll
    for (int i = 0; i < 4; ++i)
#pragma unroll
      for (int j = 0; j < 4; ++j)
        acc[i][j] = MFMA16(af[i], bfr[j], acc[i][j]);
    __syncthreads();
  }
#pragma unroll
  for (int i = 0; i < 4; ++i){
    const int row = m0 + wr*64 + i*16 + lg*4;
#pragma unroll
    for (int j = 0; j < 4; ++j){
      const int col = wc*64 + j*16 + lr;
      const float bias = fcb[col];
#pragma unroll
      for (int r = 0; r < 4; ++r)
        out[(size_t)(row + r)*NV + col] = acc[i][j][r] + bias;
    }
  }
}

extern "C" void kernel_launch(void* const* d_in, const int* in_sizes, int n_in,
                              void* d_out, int out_size, void* d_ws, size_t ws_size,
                              hipStream_t stream)
{
  const int*   x   = (const int*)  d_in[0];
  const float* emb = (const float*)d_in[1];
  const float* wxw = (const float*)d_in[2];
  const float* wxb = (const float*)d_in[3];
  const float* whw = (const float*)d_in[4];
  const float* whb = (const float*)d_in[5];
  const float* waw = (const float*)d_in[6];
  const float* wab = (const float*)d_in[7];
  const float* fcw = (const float*)d_in[8];
  const float* fcb = (const float*)d_in[9];
  float* out = (float*)d_out;

  char* ws = (char*)d_ws;
  u64*   hstate = (u64*)  (ws);                       // 512 KB: 2 parities x 32x1024 pairs
  float* XW     = (float*)(ws + 524288);              // 512 KB -> ends 1048576
  u16*   Harc   = (u16*)  (ws + 1048576);             // 64 MB  -> ends 68157440
  u16*   Aarc   = (u16*)  (ws + 68157440);            // 64 MB  -> ends 135266304 (reused as Ctx)
  u16*   SW     = (u16*)  (ws + 135266304);           // 64 MB  -> ends 202375168
  u16*   wa_bf  = (u16*)  (ws + 135266304);           // aliases SW (dead before scores)
  u16*   fc_bf  = (u16*)  (ws + 202375168);           // 512 KB -> total ~202.9 MB
  u16*   Ctx    = Aarc;                               // PV output overwrites A archive

  (void)hipMemsetAsync(ws, 0, 524288, stream);        // hstate zeros = {tag 0, 0.0f}

  k_cvt<<<dim3(5120), dim3(256), 0, stream>>>(waw, fcw, wa_bf, fc_bf);
  k_xw<<<dim3(NV), dim3(256), 0, stream>>>(emb, wxw, wxb, XW);

  {
    void* args[] = { (void*)&x, (void*)&whw, (void*)&whb, (void*)&XW,
                     (void*)&hstate, (void*)&Harc };
    (void)hipLaunchCooperativeKernel((const void*)k_scan2, dim3(256), dim3(256),
                                     args, 0, stream);
  }

  k_gemm_A<<<dim3(256, 8), dim3(256), 0, stream>>>(Harc, wa_bf, wab, Aarc);
  k_scores<<<dim3(8, 8, 32), dim3(256), 0, stream>>>(Harc, Aarc, SW);
  k_softmax<<<dim3(32768), dim3(256), 0, stream>>>(SW);
  k_pv<<<dim3(8, 8, 32), dim3(256), 0, stream>>>(SW, Harc, Ctx);
  k_out2<<<dim3(256), dim3(256), 0, stream>>>(Harc, Ctx, fc_bf, fcb, out);
}